// Round 12
// baseline (87.079 us; speedup 1.0000x reference)
//
#include <hip/hip_runtime.h>

#define HH 136
#define WW 240
#define HW (HH * WW)
#define DS 8
#define OW (DS * WW)   // 1920
#define OH (DS * HH)   // 1088
#define CROWS 9        // rows per chunk
#define NCH 8          // 8 chunks x 9 = 72 (k,j) rows
#define NBUF 3         // triple buffer: issue c+2 while computing c

typedef float vf4 __attribute__((ext_vector_type(4)));

// WAVE-PRIVATE pipelines, ZERO barriers (R8-R11 post-mortems: block-level
// levers saturated — 6->7 blocks/CU null, 2-deep dbuf +3%. The shared flaw:
// all 4 waves convoy through block barriers, and 1-chunk lookahead (~300 cyc)
// < L3-miss latency (~900 cyc), so every block stalls at its vmcnt).
//  - Each wave owns 60 px + a private LDS slice; stages its own 240 B
//    row-segments (lanes 0-14, global_load_lds) and consumes them itself:
//    same-wave vmcnt is the only sync needed. No __syncthreads anywhere.
//  - Triple buffer: issue chunk c+2, wait batch c via counted vmcnt(18)
//    (2 batches = 18 loads in flight), compute c. ~2 chunk-times of cover,
//    and 24 independent waves/CU self-stagger across SIMDs.
//  - LDS 4x3x9x60 floats = 25.9 KB -> 6 blocks/CU = 24 waves (= R11).
//  - Compute/store unchanged (no-max softmax verified R6-R11; R4 store
//    shape: thread owns 32 B/channel, dense row per block).
__device__ __forceinline__ void gload_lds16(const float* g, float* l) {
  __builtin_amdgcn_global_load_lds(
      (const __attribute__((address_space(1))) void*)g,
      (__attribute__((address_space(3))) void*)l, 16, 0, 0);
}

__global__ __launch_bounds__(256, 6) void upflow_kernel(
    const float* __restrict__ flow,
    const float* __restrict__ mask,
    float* __restrict__ out) {
  __shared__ float lm[4][NBUF][CROWS][60];  // 25920 B, wave-private slices

  int h = blockIdx.x;   // 0..135
  int ni = blockIdx.y;  // n*8 + i
  int i = ni & 7;
  int n = ni >> 3;
  int tid = threadIdx.x;
  int w = tid >> 6, lane = tid & 63;
  int px = w * 60 + lane;  // this wave's column, valid for lane < 60

  // Wave's mask segment base: (n, i, h) row + this wave's 240 B sub-span.
  const float* mrow =
      mask + ((size_t)n * 576 + i * 8) * HW + (size_t)h * WW + w * 60;

  // Flow loads FIRST (oldest in vmcnt order, so the compiler's f0-readiness
  // wait never forces staged batches to drain). 3x3 neighborhood, both
  // channels, pre-scaled, zero-padded; tiny and L2/L3-resident.
  float f0[9], f1[9];
  if (lane < 60) {
    const float* fb0 = flow + (size_t)(n * 2 + 0) * HW;
    const float* fb1 = flow + (size_t)(n * 2 + 1) * HW;
#pragma unroll
    for (int dy = 0; dy < 3; ++dy) {
      int hh = h + dy - 1;
      bool rok = (hh >= 0) && (hh < HH);
#pragma unroll
      for (int dx = 0; dx < 3; ++dx) {
        int k = dy * 3 + dx;
        int cc = px + dx - 1;
        bool ok = rok && (cc >= 0) && (cc < WW);
        int idx = hh * WW + cc;
        f0[k] = ok ? 8.0f * fb0[idx] : 0.0f;
        f1[k] = ok ? 8.0f * fb1[idx] : 0.0f;
      }
    }
  }

  // Prologue: stage chunks 0 and 1 into bufs 0,1 (9 loads each, lanes 0-14).
  if (lane < 15) {
#pragma unroll
    for (int rr = 0; rr < CROWS; ++rr) {
      gload_lds16(mrow + (size_t)((rr >> 3) * 64 + (rr & 7)) * HW + lane * 4,
                  &lm[w][0][rr][0]);
    }
#pragma unroll
    for (int rr = 0; rr < CROWS; ++rr) {
      int g = CROWS + rr;
      gload_lds16(mrow + (size_t)((g >> 3) * 64 + (g & 7)) * HW + lane * 4,
                  &lm[w][1][rr][0]);
    }
  }

  const float L2E = 1.4426950408889634f;
  float sj[8], d0j[8], d1j[8];
#pragma unroll
  for (int j = 0; j < 8; ++j) { sj[j] = 0.f; d0j[j] = 0.f; d1j[j] = 0.f; }

#pragma unroll
  for (int c = 0; c < NCH; ++c) {
    if (c + 2 < NCH) {
      // Issue chunk c+2 into buf (c+2)%3; consumed two iterations later.
      if (lane < 15) {
#pragma unroll
        for (int rr = 0; rr < CROWS; ++rr) {
          int g = (c + 2) * CROWS + rr;
          gload_lds16(
              mrow + (size_t)((g >> 3) * 64 + (g & 7)) * HW + lane * 4,
              &lm[w][(c + 2) % NBUF][rr][0]);
        }
      }
      // Batch c done; batches c+1, c+2 (2x9 = 18) stay in flight.
      asm volatile("s_waitcnt vmcnt(18)" ::: "memory");
    } else if (c + 2 == NCH) {
      asm volatile("s_waitcnt vmcnt(9)" ::: "memory");
    } else {
      asm volatile("s_waitcnt vmcnt(0)" ::: "memory");
    }
    if (lane < 60) {
#pragma unroll
      for (int rr = 0; rr < CROWS; ++rr) {
        const int g = c * CROWS + rr;     // static after unroll
        const int k = g >> 3, j = g & 7;  // static
        float e = exp2f(lm[w][c % NBUF][rr][lane] * L2E);  // no max-sub
        sj[j] += e;
        d0j[j] += e * f0[k];
        d1j[j] += e * f1[k];
      }
    }
  }

  if (lane < 60) {
    // out[n][c][h*8+i][px*8+j]: 32 B contiguous per lane per channel; block
    // writes one fully dense 1920-float row per channel (R4 shape).
    size_t ob0 =
        ((size_t)(n * 2 + 0) * OH + (size_t)(h * 8 + i)) * (size_t)OW + px * 8;
    size_t ob1 = ob0 + (size_t)OH * OW;
    float r0 = 1.0f / sj[0], r1 = 1.0f / sj[1], r2 = 1.0f / sj[2],
          r3 = 1.0f / sj[3], r4 = 1.0f / sj[4], r5 = 1.0f / sj[5],
          r6 = 1.0f / sj[6], r7 = 1.0f / sj[7];
    vf4 a = {d0j[0] * r0, d0j[1] * r1, d0j[2] * r2, d0j[3] * r3};
    vf4 b = {d0j[4] * r4, d0j[5] * r5, d0j[6] * r6, d0j[7] * r7};
    vf4 c = {d1j[0] * r0, d1j[1] * r1, d1j[2] * r2, d1j[3] * r3};
    vf4 d = {d1j[4] * r4, d1j[5] * r5, d1j[6] * r6, d1j[7] * r7};
    *(vf4*)(out + ob0) = a;
    *(vf4*)(out + ob0 + 4) = b;
    *(vf4*)(out + ob1) = c;
    *(vf4*)(out + ob1 + 4) = d;
  }
}

extern "C" void kernel_launch(void* const* d_in, const int* in_sizes, int n_in,
                              void* d_out, int out_size, void* d_ws, size_t ws_size,
                              hipStream_t stream) {
  const float* flow = (const float*)d_in[0];
  const float* mask = (const float*)d_in[1];
  float* out = (float*)d_out;
  dim3 grid(HH, 32);  // x = h, y = n*8 + i
  upflow_kernel<<<grid, 256, 0, stream>>>(flow, mask, out);
}

// Round 13
// 75.675 us; speedup vs baseline: 1.1507x; 1.1507x over previous
//
#include <hip/hip_runtime.h>

#define HH 136
#define WW 240
#define HW (HH * WW)
#define DS 8
#define OW (DS * WW)   // 1920
#define OH (DS * HH)   // 1088
#define CROWS 8        // chunk = one k: 8 j-rows
#define NCH 9          // 9 chunks (k = 0..8)
#define NBUF 3         // lookahead 2 chunks; NBUF >= L+1 with 2 barriers

typedef float vf4 __attribute__((ext_vector_type(4)));

// R11 (best, 74.7 us) deepened to a 3-buffer / lookahead-2 pipeline.
// R12 post-mortem: wave-private staging regressed because it shrank requests
// to 240 B and 4x'd VMEM instructions — keep block-wide 960 B staging.
// R11 post-mortem arithmetic: 1-chunk lookahead gives ~150 cyc of cover vs
// ~900 cyc HBM latency -> ~42% duty. Depth 2 doubles per-wave cover and
// in-flight bytes/CU at the same 23 KB LDS (7 blocks/CU).
//  - chunk c == k: compute uses scalar f0[c], f1[c].
//  - wave w stages rows j={2w,2w+1} per chunk (one 960 B gload_lds each).
//  - counted vmcnt(4): batches c+1, c+2 (2 loads each) stay in flight.
//  - two raw barriers per chunk (R11-proven safety: writes to (c+2)%3 can
//    never touch a buffer with live readers).
//  - no-max softmax (verified R6-R12); R4 store shape (thread owns 32 B per
//    channel, block writes dense 1920-float rows).
__device__ __forceinline__ void gload_lds16(const float* g, float* l) {
  __builtin_amdgcn_global_load_lds(
      (const __attribute__((address_space(1))) void*)g,
      (__attribute__((address_space(3))) void*)l, 16, 0, 0);
}

__global__ __launch_bounds__(256, 7) void upflow_kernel(
    const float* __restrict__ flow,
    const float* __restrict__ mask,
    float* __restrict__ out) {
  __shared__ float lm[NBUF][CROWS][WW];  // 23040 B -> 7 blocks/CU

  int h = blockIdx.x;   // 0..135
  int ni = blockIdx.y;  // n*8 + i
  int i = ni & 7;
  int n = ni >> 3;
  int tid = threadIdx.x;
  int w = tid >> 6, lane = tid & 63;
  int px = tid;  // compute column for tid < 240

  // Flow loads FIRST: oldest in vmcnt order, so their completion never
  // forces staged batches to drain. 3x3 neighborhood, pre-scaled, padded.
  float f0[9], f1[9];
  if (px < WW) {
    const float* fb0 = flow + (size_t)(n * 2 + 0) * HW;
    const float* fb1 = flow + (size_t)(n * 2 + 1) * HW;
#pragma unroll
    for (int dy = 0; dy < 3; ++dy) {
      int hh = h + dy - 1;
      bool rok = (hh >= 0) && (hh < HH);
#pragma unroll
      for (int dx = 0; dx < 3; ++dx) {
        int k = dy * 3 + dx;
        int cc = px + dx - 1;
        bool ok = rok && (cc >= 0) && (cc < WW);
        int idx = hh * WW + cc;
        f0[k] = ok ? 8.0f * fb0[idx] : 0.0f;
        f1[k] = ok ? 8.0f * fb1[idx] : 0.0f;
      }
    }
  }

  // mask row base for (n, i, h); channel (k*64 + i*8 + j) offset is uniform.
  const float* mrow = mask + ((size_t)n * 576 + i * 8) * HW + (size_t)h * WW;

  // Prologue: stage chunks 0 and 1 (wave w stages rows j = 2w, 2w+1).
  if (lane < 60) {
#pragma unroll
    for (int t = 0; t < 2; ++t) {
      int j = 2 * w + t;
      gload_lds16(mrow + (size_t)(0 * 64 + j) * HW + lane * 4, &lm[0][j][0]);
    }
#pragma unroll
    for (int t = 0; t < 2; ++t) {
      int j = 2 * w + t;
      gload_lds16(mrow + (size_t)(1 * 64 + j) * HW + lane * 4, &lm[1][j][0]);
    }
  }

  const float L2E = 1.4426950408889634f;
  float sj[8], d0j[8], d1j[8];
#pragma unroll
  for (int j = 0; j < 8; ++j) { sj[j] = 0.f; d0j[j] = 0.f; d1j[j] = 0.f; }

#pragma unroll
  for (int c = 0; c < NCH; ++c) {
    if (c + 2 < NCH) {
      // Issue chunk c+2 into buf (c+2)%3 (its last readers finished at the
      // barrier closing chunk c-1).
      if (lane < 60) {
#pragma unroll
        for (int t = 0; t < 2; ++t) {
          int j = 2 * w + t;
          gload_lds16(mrow + (size_t)((c + 2) * 64 + j) * HW + lane * 4,
                      &lm[(c + 2) % NBUF][j][0]);
        }
      }
      // Batch c landed; batches c+1, c+2 (4 loads) stay in flight.
      asm volatile("s_waitcnt vmcnt(4)" ::: "memory");
    } else if (c + 2 == NCH) {
      asm volatile("s_waitcnt vmcnt(2)" ::: "memory");
    } else {
      asm volatile("s_waitcnt vmcnt(0)" ::: "memory");
    }
    __builtin_amdgcn_s_barrier();   // batch c visible to all waves
    asm volatile("" ::: "memory");  // ds_reads may not hoist above

    if (px < WW) {
      const float fc0 = f0[c], fc1 = f1[c];  // chunk == k
#pragma unroll
      for (int j = 0; j < 8; ++j) {
        float e = exp2f(lm[c % NBUF][j][px] * L2E);  // no max-subtraction
        sj[j] += e;
        d0j[j] += e * fc0;
        d1j[j] += e * fc1;
      }
    }

    if (c + 1 < NCH) {
      asm volatile("" ::: "memory");  // ds_reads may not sink below
      __builtin_amdgcn_s_barrier();   // chunk-c reads done; refills legal
      asm volatile("" ::: "memory");
    }
  }

  if (px < WW) {
    // out[n][c][h*8+i][px*8+j]: 32 B contiguous per lane per channel; block
    // writes one fully dense 1920-float row per channel (R4 shape).
    size_t ob0 =
        ((size_t)(n * 2 + 0) * OH + (size_t)(h * 8 + i)) * (size_t)OW + px * 8;
    size_t ob1 = ob0 + (size_t)OH * OW;
    float r0 = 1.0f / sj[0], r1 = 1.0f / sj[1], r2 = 1.0f / sj[2],
          r3 = 1.0f / sj[3], r4 = 1.0f / sj[4], r5 = 1.0f / sj[5],
          r6 = 1.0f / sj[6], r7 = 1.0f / sj[7];
    vf4 a = {d0j[0] * r0, d0j[1] * r1, d0j[2] * r2, d0j[3] * r3};
    vf4 b = {d0j[4] * r4, d0j[5] * r5, d0j[6] * r6, d0j[7] * r7};
    vf4 c = {d1j[0] * r0, d1j[1] * r1, d1j[2] * r2, d1j[3] * r3};
    vf4 d = {d1j[4] * r4, d1j[5] * r5, d1j[6] * r6, d1j[7] * r7};
    *(vf4*)(out + ob0) = a;
    *(vf4*)(out + ob0 + 4) = b;
    *(vf4*)(out + ob1) = c;
    *(vf4*)(out + ob1 + 4) = d;
  }
}

extern "C" void kernel_launch(void* const* d_in, const int* in_sizes, int n_in,
                              void* d_out, int out_size, void* d_ws, size_t ws_size,
                              hipStream_t stream) {
  const float* flow = (const float*)d_in[0];
  const float* mask = (const float*)d_in[1];
  float* out = (float*)d_out;
  dim3 grid(HH, 32);  // x = h, y = n*8 + i
  upflow_kernel<<<grid, 256, 0, stream>>>(flow, mask, out);
}